// Round 4
// baseline (458.393 us; speedup 1.0000x reference)
//
#include <hip/hip_runtime.h>
#include <math.h>

#define NP 256   // datapoints
#define BB 128   // batch
#define DD 784   // dims
#define HS_MIN 1e-7f
#define LOG_HS_MIN -16.11809565095832f   // log(1e-7)
#define LOG_MB -16.811242831518264f      // log(5e-8) — mask bound in log space
#define NEG_HALF_LOG_2PI -0.9189385332046727f
#define W 16     // householder window
#define NW 49    // 784/16
#define TILE_F (W * DD)          // 12544 floats = 49 KiB V tile
#define BUF_F  (TILE_F + 256)    // + 256-float G tile

// ---------------- ndtri (AS241, double poly) from log_cdf / log_sf ----------------
__device__ double ndtri_logs(float log_cdf_f, float log_sf_f) {
    double lp = (double)log_cdf_f;
    double ls = (double)log_sf_f;
    double p = (double)__expf(log_cdf_f);
    double q = p - 0.5;
    if (fabs(q) <= 0.425) {
        double r = 0.180625 - q * q;
        double num = (((((((2.5090809287301226727e3 * r + 3.3430575583588128105e4) * r
                         + 6.7265770927008700853e4) * r + 4.5921953931549871457e4) * r
                         + 1.3731693765509461125e4) * r + 1.9715909503065514427e3) * r
                         + 1.3314166789178437745e2) * r + 3.3871328727963666080e0);
        double den = (((((((5.2264952788528545610e3 * r + 2.8729085735721942674e4) * r
                         + 3.9307895800092710610e4) * r + 2.1213794301586595867e4) * r
                         + 5.3941960214247511077e3) * r + 6.8718700749205790830e2) * r
                         + 4.2313330701600911252e1) * r + 1.0);
        return q * num / den;
    }
    // tail: r = sqrt(-log(min(p,1-p))) straight from the log — no 1-p cancellation
    double r = (q < 0.0) ? sqrt(-lp) : sqrt(-ls);
    double v;
    if (r <= 5.0) {
        r -= 1.6;
        double num = (((((((7.74545014278341407640e-4 * r + 2.27238449892691845833e-2) * r
                         + 2.41780725177450611770e-1) * r + 1.27045825245236838258e0) * r
                         + 3.64784832476320460504e0) * r + 5.76949722146069140550e0) * r
                         + 4.63033784615654529590e0) * r + 1.42343711074968357734e0);
        double den = (((((((1.05075007164441684324e-9 * r + 5.47593808499534494600e-4) * r
                         + 1.51986665636164571966e-2) * r + 1.48103976427480074590e-1) * r
                         + 6.89767334985100004550e-1) * r + 1.67638483018380384940e0) * r
                         + 2.05319162663775882187e0) * r + 1.0);
        v = num / den;
    } else {
        r -= 5.0;
        double num = (((((((2.01033439929228813265e-7 * r + 2.71155556874348757815e-5) * r
                         + 1.24266094738807843860e-3) * r + 2.65321895265761230930e-2) * r
                         + 2.96560571828504891230e-1) * r + 1.78482653991729133580e0) * r
                         + 5.46378491116411436990e0) * r + 6.65790464350110377720e0);
        double den = (((((((2.04426310338993978564e-15 * r + 1.42151175831644588870e-7) * r
                         + 1.84631831751005468180e-5) * r + 7.86869131145613259100e-4) * r
                         + 1.48753612908506148525e-2) * r + 1.36929880922735805310e-1) * r
                         + 5.99832206555887937690e-1) * r + 1.0);
        v = num / den;
    }
    return (q < 0.0) ? -v : v;
}

// ---------------- K0: lsew[d] = logsumexp_n kde_weights[n,d] (block per d) ----------------
__global__ __launch_bounds__(256) void k_lsew(const float* __restrict__ kw,
                                              float* __restrict__ lsew) {
    __shared__ float red[4];
    int d = blockIdx.x;
    int n = threadIdx.x;          // NP == 256 == blockDim
    float a = kw[n * DD + d];
    float m = a;
    #pragma unroll
    for (int off = 32; off; off >>= 1) m = fmaxf(m, __shfl_xor(m, off, 64));
    if ((threadIdx.x & 63) == 0) red[threadIdx.x >> 6] = m;
    __syncthreads();
    m = fmaxf(fmaxf(red[0], red[1]), fmaxf(red[2], red[3]));
    __syncthreads();
    float e = __expf(a - m);
    #pragma unroll
    for (int off = 32; off; off >>= 1) e += __shfl_xor(e, off, 64);
    if ((threadIdx.x & 63) == 0) red[threadIdx.x >> 6] = e;
    __syncthreads();
    if (threadIdx.x == 0)
        lsew[d] = m + __logf(red[0] + red[1] + red[2] + red[3]);
}

// ---------------- K1: per-(n,d) precompute, packed float4 {dp, 1/hs, w, w-lhc} ----------------
__global__ __launch_bounds__(256) void k_prep(const float* __restrict__ kw,
                                              const float* __restrict__ log_hs,
                                              const float* __restrict__ dp,
                                              const float* __restrict__ lsew,
                                              float4* __restrict__ pk) {
    int n = blockIdx.x;
    for (int d = threadIdx.x; d < DD; d += 256) {
        int idx = n * DD + d;
        float lh = log_hs[idx];
        float hs = fmaxf(__expf(lh), HS_MIN);
        float lhc = fmaxf(lh, LOG_HS_MIN);
        float wv = kw[idx] - lsew[d];
        pk[idx] = make_float4(dp[idx], 1.f / hs, wv, wv - lhc);
    }
}

// ---------------- K2: main KDE + inverse + term ----------------
__global__ __launch_bounds__(256) void k_main(const float* __restrict__ x,
                                              const float4* __restrict__ pk,
                                              float* __restrict__ Y,
                                              float* __restrict__ T) {
    unsigned t = blockIdx.x * 256u + threadIdx.x;   // t < B*D exactly
    unsigned b = t / DD;
    unsigned d = t - b * DD;
    float xv = x[t];
    float m1 = -INFINITY, s1 = 0.f;
    float m2 = -INFINITY, s2 = 0.f;
    float m3 = -INFINITY, s3 = 0.f;
    for (int n = 0; n < NP; ++n) {
        float4 c = pk[n * DD + d];          // {dp, ihs, w, w-lhc}
        float u = (c.x - xv) * c.y;
        float e = __expf(-fabsf(u));
        float l1p = __logf(1.f + e);
        float sp = fmaxf(u, 0.f) + l1p;
        float a1 = c.z - sp;
        float a2 = fminf(u, 0.f) - l1p + c.z;
        float a3 = u - 2.f * sp + c.w;
        float nm;
        nm = fmaxf(m1, a1); s1 = s1 * __expf(m1 - nm) + __expf(a1 - nm); m1 = nm;
        nm = fmaxf(m2, a2); s2 = s2 * __expf(m2 - nm) + __expf(a2 - nm); m2 = nm;
        nm = fmaxf(m3, a3); s3 = s3 * __expf(m3 - nm) + __expf(a3 - nm); m3 = nm;
    }
    float log_cdf = m1 + __logf(s1);
    float log_sf  = m2 + __logf(s2);
    float log_pdf = m3 + __logf(s3);

    // log-space mask classification (no f32 cancellation at cdf ~ 1)
    bool right = (log_sf  <= LOG_MB);
    bool left  = (log_cdf <= LOG_MB);

    float inv, lgd;
    if (right) {
        float t2 = -2.f * log_sf;
        inv = sqrtf(t2);
        lgd = 0.5f * __logf(t2) - log_sf;
    } else if (left) {
        float t2 = -2.f * log_cdf;
        inv = -sqrtf(t2);
        lgd = 0.5f * __logf(t2) - log_cdf;
    } else {
        inv = (float)ndtri_logs(log_cdf, log_sf);
        lgd = -0.5f * inv * inv + NEG_HALF_LOG_2PI;
    }
    Y[t] = inv;
    T[t] = log_pdf - lgd;
}

// ---------------- K3: log_det reduction ----------------
__global__ __launch_bounds__(256) void k_logdet(const float* __restrict__ T,
                                                const float* __restrict__ ld_in,
                                                float* __restrict__ out) {
    __shared__ float red[4];
    int b = blockIdx.x;
    float s = 0.f;
    for (int d = threadIdx.x; d < DD; d += 256) s += T[b * DD + d];
    #pragma unroll
    for (int off = 32; off; off >>= 1) s += __shfl_down(s, off, 64);
    if ((threadIdx.x & 63) == 0) red[threadIdx.x >> 6] = s;
    __syncthreads();
    if (threadIdx.x == 0) out[BB * DD + b] = ld_in[b] + red[0] + red[1] + red[2] + red[3];
}

// ---------------- K4: normalize reflector rows ----------------
__global__ __launch_bounds__(256) void k_vn(const float* __restrict__ vs,
                                            float* __restrict__ vn) {
    __shared__ float red[4];
    int i = blockIdx.x;
    float ss = 0.f;
    for (int j = threadIdx.x; j < DD; j += 256) {
        float v = vs[i * DD + j];
        ss += v * v;
    }
    #pragma unroll
    for (int off = 32; off; off >>= 1) ss += __shfl_down(ss, off, 64);
    if ((threadIdx.x & 63) == 0) red[threadIdx.x >> 6] = ss;
    __syncthreads();
    float inorm = rsqrtf(red[0] + red[1] + red[2] + red[3]);
    for (int j = threadIdx.x; j < DD; j += 256)
        vn[i * DD + j] = vs[i * DD + j] * inorm;
}

// ---------------- K5: Gram of each 16-reflector window (verbatim round-0) ----------------
__global__ __launch_bounds__(256) void k_gram(const float* __restrict__ vn,
                                              float* __restrict__ G) {
    int wi = blockIdx.x;
    int t = threadIdx.x;
    int k = t >> 4, i = t & 15;
    const float4* a = (const float4*)(vn + (wi * W + k) * DD);
    const float4* b = (const float4*)(vn + (wi * W + i) * DD);
    float s = 0.f;
    for (int j = 0; j < DD / 4; ++j) {
        float4 av = a[j], bv = b[j];
        s += av.x * bv.x + av.y * bv.y + av.z * bv.z + av.w * bv.w;
    }
    G[wi * 256 + k * 16 + i] = s;   // G[w][k][i] = v_k . v_i
}

// ---------------- K6: Householder chain — 1 wave/row, LDS double-buffer prefetch ----------------
// Same math as the verified round-2 kernel (identical values, element mapping, and
// summation order). Change vs round 2: the window's V tile (contiguous 16*784 floats
// of VN) and its 256-float G tile are staged into LDS via global_load_lds (width 16),
// double-buffered: window wi+1's 50 glds are issued right after the vmcnt(0) wait for
// window wi, so HBM/L2 latency hides under wi's ~4k-cycle compute. Single wave => no
// barriers => no compiler-forced vmcnt(0) drain (the round-0 killer). Compute reads
// V from LDS just-in-time (no 208-float register array => no rematerialization
// pathology, the round-2 killer; VGPR ~60). Static LDS (102400 B < 160 KiB/CU) so no
// dynamic-shared-mem opt-in is involved.
__device__ __forceinline__ void stage_window(const float* __restrict__ VN,
                                             const float* __restrict__ G,
                                             int wi, float* buf, int l) {
    const float* src = VN + (size_t)wi * TILE_F;   // window tile is contiguous in VN
    #pragma unroll
    for (int k = 0; k < TILE_F / 256; ++k) {       // 49 instrs x (64 lanes x 16 B) = 49 KiB
        __builtin_amdgcn_global_load_lds(
            (const __attribute__((address_space(1))) void*)(src + k * 256 + l * 4),
            (__attribute__((address_space(3))) void*)(buf + k * 256),
            16, 0, 0);
    }
    __builtin_amdgcn_global_load_lds(
        (const __attribute__((address_space(1))) void*)(G + wi * 256 + l * 4),
        (__attribute__((address_space(3))) void*)(buf + TILE_F),
        16, 0, 0);
}

__global__ __launch_bounds__(64, 1) void k_house(const float* __restrict__ Yin,
                                                 const float* __restrict__ VN,
                                                 const float* __restrict__ G,
                                                 float* __restrict__ out) {
    __shared__ float lds[2 * BUF_F];    // 102400 B static LDS
    const int b = blockIdx.x;
    const int l = threadIdx.x;
    float* bufA = lds;
    float* bufB = lds + BUF_F;

    float y[13];
    #pragma unroll
    for (int i = 0; i < 12; ++i) y[i] = Yin[b * DD + 64 * i + l];
    y[12] = (l < 16) ? Yin[b * DD + 768 + l] : 0.f;

    stage_window(VN, G, 0, bufA, l);

    for (int wi = 0; wi < NW; ++wi) {
        // wait for current buffer's staging (issued one full window ago — near-zero stall)
        asm volatile("s_waitcnt vmcnt(0)" ::: "memory");
        __builtin_amdgcn_sched_barrier(0);
        if (wi + 1 < NW) stage_window(VN, G, wi + 1, bufB, l);

        const float* Vw = bufA;
        const float* Gw = bufA + TILE_F;

        // raw dots q_r = y . v_r (same order as round 2: i = 0..12, tail masked)
        float p[W];
        #pragma unroll
        for (int r = 0; r < W; ++r) {
            const float* vr = Vw + r * DD + l;
            float s = 0.f;
            #pragma unroll
            for (int i = 0; i < 12; ++i) s += y[i] * vr[64 * i];
            s += y[12] * ((l < 16) ? vr[768] : 0.f);
            p[r] = s;
        }
        // full-wave butterfly: every lane ends with all 16 complete sums
        #pragma unroll
        for (int r = 0; r < W; ++r) {
            #pragma unroll
            for (int off = 32; off; off >>= 1) p[r] += __shfl_xor(p[r], off, 64);
        }

        // forward substitution (round-0 formula & association), redundant per lane
        float s[W];
        #pragma unroll
        for (int r = 0; r < W; ++r) {
            float acc = p[r];
            #pragma unroll
            for (int k = 0; k < W; ++k)
                if (k < r) acc -= 2.f * Gw[k * W + r] * s[k];
            s[r] = acc;
        }

        // rank-16 update (re-reads V from LDS — cheap, deterministic same bits)
        #pragma unroll
        for (int r = 0; r < W; ++r) {
            float c = 2.f * s[r];
            const float* vr = Vw + r * DD + l;
            #pragma unroll
            for (int i = 0; i < 12; ++i) y[i] -= c * vr[64 * i];
            if (l < 16) y[12] -= c * vr[768];
        }

        float* tmp = bufA; bufA = bufB; bufB = tmp;
    }

    #pragma unroll
    for (int i = 0; i < 12; ++i) out[b * DD + 64 * i + l] = y[i];
    if (l < 16) out[b * DD + 768 + l] = y[12];
}

// ---------------- launch ----------------
extern "C" void kernel_launch(void* const* d_in, const int* in_sizes, int n_in,
                              void* d_out, int out_size, void* d_ws, size_t ws_size,
                              hipStream_t stream) {
    const float* x      = (const float*)d_in[0];   // [B,D]
    const float* ld_in  = (const float*)d_in[1];   // [B]
    const float* dp     = (const float*)d_in[2];   // [N,D]
    const float* log_hs = (const float*)d_in[3];   // [N,D]
    const float* kw     = (const float*)d_in[4];   // [N,D]
    const float* vs     = (const float*)d_in[5];   // [D,D]
    float* out = (float*)d_out;                    // x_out [B,D] then log_det [B]

    float* ws   = (float*)d_ws;
    float* lsew = ws;                         // 784 (pad to 1024)
    float4* pk  = (float4*)(ws + 1024);       // N*D float4
    float* Y    = ws + 1024 + NP * DD * 4;    // B*D
    float* T    = Y + BB * DD;                // B*D
    float* VN   = T + BB * DD;                // D*D
    float* G    = VN + DD * DD;               // NW*256

    k_lsew<<<DD, 256, 0, stream>>>(kw, lsew);
    k_prep<<<NP, 256, 0, stream>>>(kw, log_hs, dp, lsew, pk);
    k_main<<<(BB * DD) / 256, 256, 0, stream>>>(x, pk, Y, T);
    k_logdet<<<BB, 256, 0, stream>>>(T, ld_in, out);
    k_vn<<<DD, 256, 0, stream>>>(vs, VN);
    k_gram<<<NW, 256, 0, stream>>>(VN, G);
    k_house<<<BB, 64, 0, stream>>>(Y, VN, G, out);
}

// Round 5
// 452.903 us; speedup vs baseline: 1.0121x; 1.0121x over previous
//
#include <hip/hip_runtime.h>
#include <math.h>

#define NP 256   // datapoints
#define BB 128   // batch
#define DD 784   // dims
#define HS_MIN 1e-7f
#define LOG_HS_MIN -16.11809565095832f   // log(1e-7)
#define LOG_MB -16.811242831518264f      // log(5e-8) — mask bound in log space
#define NEG_HALF_LOG_2PI -0.9189385332046727f
#define W 16     // householder window
#define NW 49    // 784/16
#define TILE_F (W * DD)          // 12544 floats = 49 KiB V tile
#define BUF_F  (TILE_F + 256)    // + 256-float G tile
#define RPB 4    // rows (waves) per block

// ---------------- ndtri (AS241, double poly) from log_cdf / log_sf ----------------
__device__ double ndtri_logs(float log_cdf_f, float log_sf_f) {
    double lp = (double)log_cdf_f;
    double ls = (double)log_sf_f;
    double p = (double)__expf(log_cdf_f);
    double q = p - 0.5;
    if (fabs(q) <= 0.425) {
        double r = 0.180625 - q * q;
        double num = (((((((2.5090809287301226727e3 * r + 3.3430575583588128105e4) * r
                         + 6.7265770927008700853e4) * r + 4.5921953931549871457e4) * r
                         + 1.3731693765509461125e4) * r + 1.9715909503065514427e3) * r
                         + 1.3314166789178437745e2) * r + 3.3871328727963666080e0);
        double den = (((((((5.2264952788528545610e3 * r + 2.8729085735721942674e4) * r
                         + 3.9307895800092710610e4) * r + 2.1213794301586595867e4) * r
                         + 5.3941960214247511077e3) * r + 6.8718700749205790830e2) * r
                         + 4.2313330701600911252e1) * r + 1.0);
        return q * num / den;
    }
    // tail: r = sqrt(-log(min(p,1-p))) straight from the log — no 1-p cancellation
    double r = (q < 0.0) ? sqrt(-lp) : sqrt(-ls);
    double v;
    if (r <= 5.0) {
        r -= 1.6;
        double num = (((((((7.74545014278341407640e-4 * r + 2.27238449892691845833e-2) * r
                         + 2.41780725177450611770e-1) * r + 1.27045825245236838258e0) * r
                         + 3.64784832476320460504e0) * r + 5.76949722146069140550e0) * r
                         + 4.63033784615654529590e0) * r + 1.42343711074968357734e0);
        double den = (((((((1.05075007164441684324e-9 * r + 5.47593808499534494600e-4) * r
                         + 1.51986665636164571966e-2) * r + 1.48103976427480074590e-1) * r
                         + 6.89767334985100004550e-1) * r + 1.67638483018380384940e0) * r
                         + 2.05319162663775882187e0) * r + 1.0);
        v = num / den;
    } else {
        r -= 5.0;
        double num = (((((((2.01033439929228813265e-7 * r + 2.71155556874348757815e-5) * r
                         + 1.24266094738807843860e-3) * r + 2.65321895265761230930e-2) * r
                         + 2.96560571828504891230e-1) * r + 1.78482653991729133580e0) * r
                         + 5.46378491116411436990e0) * r + 6.65790464350110377720e0);
        double den = (((((((2.04426310338993978564e-15 * r + 1.42151175831644588870e-7) * r
                         + 1.84631831751005468180e-5) * r + 7.86869131145613259100e-4) * r
                         + 1.48753612908506148525e-2) * r + 1.36929880922735805310e-1) * r
                         + 5.99832206555887937690e-1) * r + 1.0);
        v = num / den;
    }
    return (q < 0.0) ? -v : v;
}

// ---------------- K0: lsew[d] = logsumexp_n kde_weights[n,d] (block per d) ----------------
__global__ __launch_bounds__(256) void k_lsew(const float* __restrict__ kw,
                                              float* __restrict__ lsew) {
    __shared__ float red[4];
    int d = blockIdx.x;
    int n = threadIdx.x;          // NP == 256 == blockDim
    float a = kw[n * DD + d];
    float m = a;
    #pragma unroll
    for (int off = 32; off; off >>= 1) m = fmaxf(m, __shfl_xor(m, off, 64));
    if ((threadIdx.x & 63) == 0) red[threadIdx.x >> 6] = m;
    __syncthreads();
    m = fmaxf(fmaxf(red[0], red[1]), fmaxf(red[2], red[3]));
    __syncthreads();
    float e = __expf(a - m);
    #pragma unroll
    for (int off = 32; off; off >>= 1) e += __shfl_xor(e, off, 64);
    if ((threadIdx.x & 63) == 0) red[threadIdx.x >> 6] = e;
    __syncthreads();
    if (threadIdx.x == 0)
        lsew[d] = m + __logf(red[0] + red[1] + red[2] + red[3]);
}

// ---------------- K1: per-(n,d) precompute, packed float4 {dp, 1/hs, w, w-lhc} ----------------
__global__ __launch_bounds__(256) void k_prep(const float* __restrict__ kw,
                                              const float* __restrict__ log_hs,
                                              const float* __restrict__ dp,
                                              const float* __restrict__ lsew,
                                              float4* __restrict__ pk) {
    int n = blockIdx.x;
    for (int d = threadIdx.x; d < DD; d += 256) {
        int idx = n * DD + d;
        float lh = log_hs[idx];
        float hs = fmaxf(__expf(lh), HS_MIN);
        float lhc = fmaxf(lh, LOG_HS_MIN);
        float wv = kw[idx] - lsew[d];
        pk[idx] = make_float4(dp[idx], 1.f / hs, wv, wv - lhc);
    }
}

// ---------------- K2: main KDE + inverse + term ----------------
__global__ __launch_bounds__(256) void k_main(const float* __restrict__ x,
                                              const float4* __restrict__ pk,
                                              float* __restrict__ Y,
                                              float* __restrict__ T) {
    unsigned t = blockIdx.x * 256u + threadIdx.x;   // t < B*D exactly
    unsigned b = t / DD;
    unsigned d = t - b * DD;
    float xv = x[t];
    float m1 = -INFINITY, s1 = 0.f;
    float m2 = -INFINITY, s2 = 0.f;
    float m3 = -INFINITY, s3 = 0.f;
    for (int n = 0; n < NP; ++n) {
        float4 c = pk[n * DD + d];          // {dp, ihs, w, w-lhc}
        float u = (c.x - xv) * c.y;
        float e = __expf(-fabsf(u));
        float l1p = __logf(1.f + e);
        float sp = fmaxf(u, 0.f) + l1p;
        float a1 = c.z - sp;
        float a2 = fminf(u, 0.f) - l1p + c.z;
        float a3 = u - 2.f * sp + c.w;
        float nm;
        nm = fmaxf(m1, a1); s1 = s1 * __expf(m1 - nm) + __expf(a1 - nm); m1 = nm;
        nm = fmaxf(m2, a2); s2 = s2 * __expf(m2 - nm) + __expf(a2 - nm); m2 = nm;
        nm = fmaxf(m3, a3); s3 = s3 * __expf(m3 - nm) + __expf(a3 - nm); m3 = nm;
    }
    float log_cdf = m1 + __logf(s1);
    float log_sf  = m2 + __logf(s2);
    float log_pdf = m3 + __logf(s3);

    // log-space mask classification (no f32 cancellation at cdf ~ 1)
    bool right = (log_sf  <= LOG_MB);
    bool left  = (log_cdf <= LOG_MB);

    float inv, lgd;
    if (right) {
        float t2 = -2.f * log_sf;
        inv = sqrtf(t2);
        lgd = 0.5f * __logf(t2) - log_sf;
    } else if (left) {
        float t2 = -2.f * log_cdf;
        inv = -sqrtf(t2);
        lgd = 0.5f * __logf(t2) - log_cdf;
    } else {
        inv = (float)ndtri_logs(log_cdf, log_sf);
        lgd = -0.5f * inv * inv + NEG_HALF_LOG_2PI;
    }
    Y[t] = inv;
    T[t] = log_pdf - lgd;
}

// ---------------- K3: log_det reduction ----------------
__global__ __launch_bounds__(256) void k_logdet(const float* __restrict__ T,
                                                const float* __restrict__ ld_in,
                                                float* __restrict__ out) {
    __shared__ float red[4];
    int b = blockIdx.x;
    float s = 0.f;
    for (int d = threadIdx.x; d < DD; d += 256) s += T[b * DD + d];
    #pragma unroll
    for (int off = 32; off; off >>= 1) s += __shfl_down(s, off, 64);
    if ((threadIdx.x & 63) == 0) red[threadIdx.x >> 6] = s;
    __syncthreads();
    if (threadIdx.x == 0) out[BB * DD + b] = ld_in[b] + red[0] + red[1] + red[2] + red[3];
}

// ---------------- K4: normalize reflector rows ----------------
__global__ __launch_bounds__(256) void k_vn(const float* __restrict__ vs,
                                            float* __restrict__ vn) {
    __shared__ float red[4];
    int i = blockIdx.x;
    float ss = 0.f;
    for (int j = threadIdx.x; j < DD; j += 256) {
        float v = vs[i * DD + j];
        ss += v * v;
    }
    #pragma unroll
    for (int off = 32; off; off >>= 1) ss += __shfl_down(ss, off, 64);
    if ((threadIdx.x & 63) == 0) red[threadIdx.x >> 6] = ss;
    __syncthreads();
    float inorm = rsqrtf(red[0] + red[1] + red[2] + red[3]);
    for (int j = threadIdx.x; j < DD; j += 256)
        vn[i * DD + j] = vs[i * DD + j] * inorm;
}

// ---------------- K5: Gram of each 16-reflector window (verbatim round-0) ----------------
__global__ __launch_bounds__(256) void k_gram(const float* __restrict__ vn,
                                              float* __restrict__ G) {
    int wi = blockIdx.x;
    int t = threadIdx.x;
    int k = t >> 4, i = t & 15;
    const float4* a = (const float4*)(vn + (wi * W + k) * DD);
    const float4* b = (const float4*)(vn + (wi * W + i) * DD);
    float s = 0.f;
    for (int j = 0; j < DD / 4; ++j) {
        float4 av = a[j], bv = b[j];
        s += av.x * bv.x + av.y * bv.y + av.z * bv.z + av.w * bv.w;
    }
    G[wi * 256 + k * 16 + i] = s;   // G[w][k][i] = v_k . v_i
}

// ---------------- K6: Householder chain — 4 rows/block (4 waves), shared LDS tile ----------------
// Diagnosis across rounds 0/2/4: every 1-wave-per-CU variant lands at 10-14k cy/window
// because a single wave hides NO latency (global or LDS). Fix = TLP: 4 waves per block,
// each wave running the BIT-IDENTICAL round-2 per-row computation (same lane mapping,
// dot order, butterfly, substitution, update), sharing one LDS-staged V tile.
// One __syncthreads per window; its implicit vmcnt(0) drain is free because the drained
// global_load_lds ops were issued a full window (~2k cy) earlier. While one wave waits
// on a ds_read/shuffle chain, the other 3 issue -> LDS-pipe-bound at ~2.5k cy/window.
__device__ __forceinline__ void stage_window(const float* __restrict__ VN,
                                             const float* __restrict__ G,
                                             int wi, float* buf, int l, int wv) {
    const float* src = VN + (size_t)wi * TILE_F;   // window tile is contiguous in VN
    // 50 chunks (49 V + 1 G); chunk c staged by wave c&3; 16 B/lane per chunk
    for (int c = wv; c < 50; c += RPB) {
        const float* gsrc = (c < 49) ? (src + c * 256 + l * 4)
                                     : (G + wi * 256 + l * 4);
        __builtin_amdgcn_global_load_lds(
            (const __attribute__((address_space(1))) void*)gsrc,
            (__attribute__((address_space(3))) void*)(buf + c * 256),
            16, 0, 0);
    }
}

__global__ __launch_bounds__(256, 1) void k_house(const float* __restrict__ Yin,
                                                  const float* __restrict__ VN,
                                                  const float* __restrict__ G,
                                                  float* __restrict__ out) {
    __shared__ float lds[2 * BUF_F];    // 102400 B static LDS
    const int tid = threadIdx.x;
    const int l = tid & 63;
    const int wv = tid >> 6;
    const int b = blockIdx.x * RPB + wv;   // wave wv owns batch row b

    float y[13];
    #pragma unroll
    for (int i = 0; i < 12; ++i) y[i] = Yin[b * DD + 64 * i + l];
    y[12] = (l < 16) ? Yin[b * DD + 768 + l] : 0.f;

    stage_window(VN, G, 0, lds, l, wv);

    for (int wi = 0; wi < NW; ++wi) {
        // barrier: (a) all waves' tile-wi glds drained (issued >= 1 window ago — free),
        // (b) all waves done reading tile wi-1's buffer before it is overwritten next.
        __syncthreads();
        if (wi + 1 < NW)
            stage_window(VN, G, wi + 1, lds + ((wi + 1) & 1) * BUF_F, l, wv);

        const float* Vw = lds + (wi & 1) * BUF_F;
        const float* Gw = Vw + TILE_F;

        // raw dots q_r = y . v_r (identical order to round 2)
        float p[W];
        #pragma unroll
        for (int r = 0; r < W; ++r) {
            const float* vr = Vw + r * DD + l;
            float s = 0.f;
            #pragma unroll
            for (int i = 0; i < 12; ++i) s += y[i] * vr[64 * i];
            s += y[12] * ((l < 16) ? vr[768] : 0.f);
            p[r] = s;
        }
        // full-wave butterfly: every lane ends with all 16 complete sums
        #pragma unroll
        for (int r = 0; r < W; ++r) {
            #pragma unroll
            for (int off = 32; off; off >>= 1) p[r] += __shfl_xor(p[r], off, 64);
        }

        // forward substitution (round-0 formula & association), redundant per lane
        float s[W];
        #pragma unroll
        for (int r = 0; r < W; ++r) {
            float acc = p[r];
            #pragma unroll
            for (int k = 0; k < W; ++k)
                if (k < r) acc -= 2.f * Gw[k * W + r] * s[k];
            s[r] = acc;
        }

        // rank-16 update
        #pragma unroll
        for (int r = 0; r < W; ++r) {
            float c = 2.f * s[r];
            const float* vr = Vw + r * DD + l;
            #pragma unroll
            for (int i = 0; i < 12; ++i) y[i] -= c * vr[64 * i];
            if (l < 16) y[12] -= c * vr[768];
        }
    }

    #pragma unroll
    for (int i = 0; i < 12; ++i) out[b * DD + 64 * i + l] = y[i];
    if (l < 16) out[b * DD + 768 + l] = y[12];
}

// ---------------- launch ----------------
extern "C" void kernel_launch(void* const* d_in, const int* in_sizes, int n_in,
                              void* d_out, int out_size, void* d_ws, size_t ws_size,
                              hipStream_t stream) {
    const float* x      = (const float*)d_in[0];   // [B,D]
    const float* ld_in  = (const float*)d_in[1];   // [B]
    const float* dp     = (const float*)d_in[2];   // [N,D]
    const float* log_hs = (const float*)d_in[3];   // [N,D]
    const float* kw     = (const float*)d_in[4];   // [N,D]
    const float* vs     = (const float*)d_in[5];   // [D,D]
    float* out = (float*)d_out;                    // x_out [B,D] then log_det [B]

    float* ws   = (float*)d_ws;
    float* lsew = ws;                         // 784 (pad to 1024)
    float4* pk  = (float4*)(ws + 1024);       // N*D float4
    float* Y    = ws + 1024 + NP * DD * 4;    // B*D
    float* T    = Y + BB * DD;                // B*D
    float* VN   = T + BB * DD;                // D*D
    float* G    = VN + DD * DD;               // NW*256

    k_lsew<<<DD, 256, 0, stream>>>(kw, lsew);
    k_prep<<<NP, 256, 0, stream>>>(kw, log_hs, dp, lsew, pk);
    k_main<<<(BB * DD) / 256, 256, 0, stream>>>(x, pk, Y, T);
    k_logdet<<<BB, 256, 0, stream>>>(T, ld_in, out);
    k_vn<<<DD, 256, 0, stream>>>(vs, VN);
    k_gram<<<NW, 256, 0, stream>>>(VN, G);
    k_house<<<BB / RPB, 256, 0, stream>>>(Y, VN, G, out);
}

// Round 6
// 351.582 us; speedup vs baseline: 1.3038x; 1.2882x over previous
//
#include <hip/hip_runtime.h>
#include <math.h>

#define NP 256   // datapoints
#define BB 128   // batch
#define DD 784   // dims
#define HS_MIN 1e-7f
#define LOG_HS_MIN -16.11809565095832f   // log(1e-7)
#define LOG_MB -16.811242831518264f      // log(5e-8) — mask bound in log space
#define NEG_HALF_LOG_2PI -0.9189385332046727f
#define W 8      // householder window (register-resident V)
#define NW 98    // 784/8

// ---------------- ndtri (AS241, double poly) from log_cdf / log_sf ----------------
__device__ double ndtri_logs(float log_cdf_f, float log_sf_f) {
    double lp = (double)log_cdf_f;
    double ls = (double)log_sf_f;
    double p = (double)__expf(log_cdf_f);
    double q = p - 0.5;
    if (fabs(q) <= 0.425) {
        double r = 0.180625 - q * q;
        double num = (((((((2.5090809287301226727e3 * r + 3.3430575583588128105e4) * r
                         + 6.7265770927008700853e4) * r + 4.5921953931549871457e4) * r
                         + 1.3731693765509461125e4) * r + 1.9715909503065514427e3) * r
                         + 1.3314166789178437745e2) * r + 3.3871328727963666080e0);
        double den = (((((((5.2264952788528545610e3 * r + 2.8729085735721942674e4) * r
                         + 3.9307895800092710610e4) * r + 2.1213794301586595867e4) * r
                         + 5.3941960214247511077e3) * r + 6.8718700749205790830e2) * r
                         + 4.2313330701600911252e1) * r + 1.0);
        return q * num / den;
    }
    // tail: r = sqrt(-log(min(p,1-p))) straight from the log — no 1-p cancellation
    double r = (q < 0.0) ? sqrt(-lp) : sqrt(-ls);
    double v;
    if (r <= 5.0) {
        r -= 1.6;
        double num = (((((((7.74545014278341407640e-4 * r + 2.27238449892691845833e-2) * r
                         + 2.41780725177450611770e-1) * r + 1.27045825245236838258e0) * r
                         + 3.64784832476320460504e0) * r + 5.76949722146069140550e0) * r
                         + 4.63033784615654529590e0) * r + 1.42343711074968357734e0);
        double den = (((((((1.05075007164441684324e-9 * r + 5.47593808499534494600e-4) * r
                         + 1.51986665636164571966e-2) * r + 1.48103976427480074590e-1) * r
                         + 6.89767334985100004550e-1) * r + 1.67638483018380384940e0) * r
                         + 2.05319162663775882187e0) * r + 1.0);
        v = num / den;
    } else {
        r -= 5.0;
        double num = (((((((2.01033439929228813265e-7 * r + 2.71155556874348757815e-5) * r
                         + 1.24266094738807843860e-3) * r + 2.65321895265761230930e-2) * r
                         + 2.96560571828504891230e-1) * r + 1.78482653991729133580e0) * r
                         + 5.46378491116411436990e0) * r + 6.65790464350110377720e0);
        double den = (((((((2.04426310338993978564e-15 * r + 1.42151175831644588870e-7) * r
                         + 1.84631831751005468180e-5) * r + 7.86869131145613259100e-4) * r
                         + 1.48753612908506148525e-2) * r + 1.36929880922735805310e-1) * r
                         + 5.99832206555887937690e-1) * r + 1.0);
        v = num / den;
    }
    return (q < 0.0) ? -v : v;
}

// ---------------- K0: lsew[d] = logsumexp_n kde_weights[n,d] (block per d) ----------------
__global__ __launch_bounds__(256) void k_lsew(const float* __restrict__ kw,
                                              float* __restrict__ lsew) {
    __shared__ float red[4];
    int d = blockIdx.x;
    int n = threadIdx.x;          // NP == 256 == blockDim
    float a = kw[n * DD + d];
    float m = a;
    #pragma unroll
    for (int off = 32; off; off >>= 1) m = fmaxf(m, __shfl_xor(m, off, 64));
    if ((threadIdx.x & 63) == 0) red[threadIdx.x >> 6] = m;
    __syncthreads();
    m = fmaxf(fmaxf(red[0], red[1]), fmaxf(red[2], red[3]));
    __syncthreads();
    float e = __expf(a - m);
    #pragma unroll
    for (int off = 32; off; off >>= 1) e += __shfl_xor(e, off, 64);
    if ((threadIdx.x & 63) == 0) red[threadIdx.x >> 6] = e;
    __syncthreads();
    if (threadIdx.x == 0)
        lsew[d] = m + __logf(red[0] + red[1] + red[2] + red[3]);
}

// ---------------- K1: per-(n,d) precompute, packed float4 {dp, 1/hs, w, w-lhc} ----------------
__global__ __launch_bounds__(256) void k_prep(const float* __restrict__ kw,
                                              const float* __restrict__ log_hs,
                                              const float* __restrict__ dp,
                                              const float* __restrict__ lsew,
                                              float4* __restrict__ pk) {
    int n = blockIdx.x;
    for (int d = threadIdx.x; d < DD; d += 256) {
        int idx = n * DD + d;
        float lh = log_hs[idx];
        float hs = fmaxf(__expf(lh), HS_MIN);
        float lhc = fmaxf(lh, LOG_HS_MIN);
        float wv = kw[idx] - lsew[d];
        pk[idx] = make_float4(dp[idx], 1.f / hs, wv, wv - lhc);
    }
}

// ---------------- K2: main KDE + inverse + term ----------------
__global__ __launch_bounds__(256) void k_main(const float* __restrict__ x,
                                              const float4* __restrict__ pk,
                                              float* __restrict__ Y,
                                              float* __restrict__ T) {
    unsigned t = blockIdx.x * 256u + threadIdx.x;   // t < B*D exactly
    unsigned b = t / DD;
    unsigned d = t - b * DD;
    float xv = x[t];
    float m1 = -INFINITY, s1 = 0.f;
    float m2 = -INFINITY, s2 = 0.f;
    float m3 = -INFINITY, s3 = 0.f;
    for (int n = 0; n < NP; ++n) {
        float4 c = pk[n * DD + d];          // {dp, ihs, w, w-lhc}
        float u = (c.x - xv) * c.y;
        float e = __expf(-fabsf(u));
        float l1p = __logf(1.f + e);
        float sp = fmaxf(u, 0.f) + l1p;
        float a1 = c.z - sp;
        float a2 = fminf(u, 0.f) - l1p + c.z;
        float a3 = u - 2.f * sp + c.w;
        float nm;
        nm = fmaxf(m1, a1); s1 = s1 * __expf(m1 - nm) + __expf(a1 - nm); m1 = nm;
        nm = fmaxf(m2, a2); s2 = s2 * __expf(m2 - nm) + __expf(a2 - nm); m2 = nm;
        nm = fmaxf(m3, a3); s3 = s3 * __expf(m3 - nm) + __expf(a3 - nm); m3 = nm;
    }
    float log_cdf = m1 + __logf(s1);
    float log_sf  = m2 + __logf(s2);
    float log_pdf = m3 + __logf(s3);

    // log-space mask classification (no f32 cancellation at cdf ~ 1)
    bool right = (log_sf  <= LOG_MB);
    bool left  = (log_cdf <= LOG_MB);

    float inv, lgd;
    if (right) {
        float t2 = -2.f * log_sf;
        inv = sqrtf(t2);
        lgd = 0.5f * __logf(t2) - log_sf;
    } else if (left) {
        float t2 = -2.f * log_cdf;
        inv = -sqrtf(t2);
        lgd = 0.5f * __logf(t2) - log_cdf;
    } else {
        inv = (float)ndtri_logs(log_cdf, log_sf);
        lgd = -0.5f * inv * inv + NEG_HALF_LOG_2PI;
    }
    Y[t] = inv;
    T[t] = log_pdf - lgd;
}

// ---------------- K3: log_det reduction ----------------
__global__ __launch_bounds__(256) void k_logdet(const float* __restrict__ T,
                                                const float* __restrict__ ld_in,
                                                float* __restrict__ out) {
    __shared__ float red[4];
    int b = blockIdx.x;
    float s = 0.f;
    for (int d = threadIdx.x; d < DD; d += 256) s += T[b * DD + d];
    #pragma unroll
    for (int off = 32; off; off >>= 1) s += __shfl_down(s, off, 64);
    if ((threadIdx.x & 63) == 0) red[threadIdx.x >> 6] = s;
    __syncthreads();
    if (threadIdx.x == 0) out[BB * DD + b] = ld_in[b] + red[0] + red[1] + red[2] + red[3];
}

// ---------------- K4: normalize reflector rows ----------------
__global__ __launch_bounds__(256) void k_vn(const float* __restrict__ vs,
                                            float* __restrict__ vn) {
    __shared__ float red[4];
    int i = blockIdx.x;
    float ss = 0.f;
    for (int j = threadIdx.x; j < DD; j += 256) {
        float v = vs[i * DD + j];
        ss += v * v;
    }
    #pragma unroll
    for (int off = 32; off; off >>= 1) ss += __shfl_down(ss, off, 64);
    if ((threadIdx.x & 63) == 0) red[threadIdx.x >> 6] = ss;
    __syncthreads();
    float inorm = rsqrtf(red[0] + red[1] + red[2] + red[3]);
    for (int j = threadIdx.x; j < DD; j += 256)
        vn[i * DD + j] = vs[i * DD + j] * inorm;
}

// ---------------- K5: Gram of each 8-reflector window (same math, W=8 blocks) ----------------
__global__ __launch_bounds__(64) void k_gram(const float* __restrict__ vn,
                                             float* __restrict__ G) {
    int wi = blockIdx.x;          // 0..97
    int t = threadIdx.x;          // 64 = 8x8
    int k = t >> 3, i = t & 7;
    const float4* a = (const float4*)(vn + (wi * W + k) * DD);
    const float4* b = (const float4*)(vn + (wi * W + i) * DD);
    float s = 0.f;
    for (int j = 0; j < DD / 4; ++j) {
        float4 av = a[j], bv = b[j];
        s += av.x * bv.x + av.y * bv.y + av.z * bv.z + av.w * bv.w;
    }
    G[wi * 64 + k * 8 + i] = s;   // G[w][k][i] = v_k . v_i
}

// ---------------- K6: Householder chain — 1 wave/row, W=8, register-resident V ----------------
// Diagnosis rounds 0/2/4/5: V flowed through a per-lane memory pipe TWICE per row-window
// (dot + update), ~480 pipe-ops/row-window -> all variants stuck at 10-14k cy/window.
// Fix: W=8 so the window's V (8 rows x 13 lane-elems = 104 floats) lives in REGISTERS
// across both phases (read once), loaded as float4 (3-4 dwordx4/row from L2-resident VN).
// W=8 is algebraically identical to the verified W=16 chain: the W=16 forward
// substitution splits exactly into two 8-chains when dots are taken against the
// half-updated y (q'_r = p_r - 2*sum_{k<8} G[k][r] s_k). Same G-substitution form,
// same 2*s association. Lane l owns elements {4l+256i, i<3}; tail 768..783 on lanes 0-3.
// No LDS, no barriers; 128 single-wave blocks spread over the chip.
__global__ __launch_bounds__(64, 1) void k_house(const float* __restrict__ Yin,
                                                 const float* __restrict__ VN,
                                                 const float* __restrict__ G,
                                                 float* __restrict__ out) {
    const int b = blockIdx.x;
    const int l = threadIdx.x;
    const int lt = l & 3;                 // tail lane slot (valid when l < 4)

    float4 y[3], yt;
    #pragma unroll
    for (int i = 0; i < 3; ++i)
        y[i] = *(const float4*)(Yin + b * DD + 256 * i + 4 * l);
    yt = *(const float4*)(Yin + b * DD + 768 + 4 * lt);   // lanes >=4 hold a dup; masked in dots
    if (l >= 4) yt = make_float4(0.f, 0.f, 0.f, 0.f);

    for (int wi = 0; wi < NW; ++wi) {
        const float* Vw = VN + (size_t)wi * (W * DD);
        const float* Gw = G + wi * 64;

        // load window's 8 V rows into registers (float4, L2-resident, read ONCE)
        float4 v[W][3], vt[W];
        #pragma unroll
        for (int r = 0; r < W; ++r) {
            const float* vr = Vw + r * DD;
            #pragma unroll
            for (int i = 0; i < 3; ++i)
                v[r][i] = *(const float4*)(vr + 256 * i + 4 * l);
            vt[r] = *(const float4*)(vr + 768 + 4 * lt);
        }

        // raw dots q_r = y . v_r (per-lane partial over owned elements)
        float p[W];
        #pragma unroll
        for (int r = 0; r < W; ++r) {
            float s = 0.f;
            #pragma unroll
            for (int i = 0; i < 3; ++i) {
                s += y[i].x * v[r][i].x + y[i].y * v[r][i].y
                   + y[i].z * v[r][i].z + y[i].w * v[r][i].w;
            }
            if (l < 4)
                s += yt.x * vt[r].x + yt.y * vt[r].y + yt.z * vt[r].z + yt.w * vt[r].w;
            p[r] = s;
        }
        // full-wave butterfly: every lane ends with all 8 complete sums
        #pragma unroll
        for (int r = 0; r < W; ++r) {
            #pragma unroll
            for (int off = 32; off; off >>= 1) p[r] += __shfl_xor(p[r], off, 64);
        }

        // forward substitution (same formula & association as verified rounds)
        float s[W];
        #pragma unroll
        for (int r = 0; r < W; ++r) {
            float acc = p[r];
            #pragma unroll
            for (int k = 0; k < W; ++k)
                if (k < r) acc -= 2.f * Gw[k * 8 + r] * s[k];
            s[r] = acc;
        }

        // rank-8 update from the register copy of V
        #pragma unroll
        for (int r = 0; r < W; ++r) {
            float c = 2.f * s[r];
            #pragma unroll
            for (int i = 0; i < 3; ++i) {
                y[i].x -= c * v[r][i].x;  y[i].y -= c * v[r][i].y;
                y[i].z -= c * v[r][i].z;  y[i].w -= c * v[r][i].w;
            }
            yt.x -= c * vt[r].x;  yt.y -= c * vt[r].y;
            yt.z -= c * vt[r].z;  yt.w -= c * vt[r].w;   // lanes>=4: junk, never stored/read
        }
    }

    #pragma unroll
    for (int i = 0; i < 3; ++i)
        *(float4*)(out + b * DD + 256 * i + 4 * l) = y[i];
    if (l < 4)
        *(float4*)(out + b * DD + 768 + 4 * l) = yt;
}

// ---------------- launch ----------------
extern "C" void kernel_launch(void* const* d_in, const int* in_sizes, int n_in,
                              void* d_out, int out_size, void* d_ws, size_t ws_size,
                              hipStream_t stream) {
    const float* x      = (const float*)d_in[0];   // [B,D]
    const float* ld_in  = (const float*)d_in[1];   // [B]
    const float* dp     = (const float*)d_in[2];   // [N,D]
    const float* log_hs = (const float*)d_in[3];   // [N,D]
    const float* kw     = (const float*)d_in[4];   // [N,D]
    const float* vs     = (const float*)d_in[5];   // [D,D]
    float* out = (float*)d_out;                    // x_out [B,D] then log_det [B]

    float* ws   = (float*)d_ws;
    float* lsew = ws;                         // 784 (pad to 1024)
    float4* pk  = (float4*)(ws + 1024);       // N*D float4
    float* Y    = ws + 1024 + NP * DD * 4;    // B*D
    float* T    = Y + BB * DD;                // B*D
    float* VN   = T + BB * DD;                // D*D
    float* G    = VN + DD * DD;               // NW*64 = 6272

    k_lsew<<<DD, 256, 0, stream>>>(kw, lsew);
    k_prep<<<NP, 256, 0, stream>>>(kw, log_hs, dp, lsew, pk);
    k_main<<<(BB * DD) / 256, 256, 0, stream>>>(x, pk, Y, T);
    k_logdet<<<BB, 256, 0, stream>>>(T, ld_in, out);
    k_vn<<<DD, 256, 0, stream>>>(vs, VN);
    k_gram<<<NW, 64, 0, stream>>>(VN, G);
    k_house<<<BB, 64, 0, stream>>>(Y, VN, G, out);
}